// Round 8
// baseline (559.815 us; speedup 1.0000x reference)
//
#include <hip/hip_runtime.h>
#include <math.h>

// PEER: product-key expert retrieval.
// Score path replicates numpy fp32 reference bit-for-bit (sequential-k FMA
// chain for q-GEMM; SSE 4-lane mul/add partials for einsum; fp32 adds for
// combined scores). Selection then matches np exactly. Value path fp64-accum.
// R8: qgemm register tile 8x8 -> 16x8 (128-thr blocks). LDS-port-bound
// analysis: reads/kk drop from 4/64FMA to 6/128FMA -> floor 197->143 us.

#define DIMV 1024

// ---------------- K1: rmsnorm: fp64 norm, fp32 elementwise x/n*32 ----------
__global__ __launch_bounds__(256) void peer_rmsnorm(const float* __restrict__ x,
                                                    const float* __restrict__ gamma,
                                                    float* __restrict__ xnf)
{
    int t = blockIdx.x;
    int tid = threadIdx.x;
    const float4* xr = (const float4*)(x + (size_t)t * DIMV);
    float4 v = xr[tid];
    double ss = (double)v.x*v.x + (double)v.y*v.y + (double)v.z*v.z + (double)v.w*v.w;
    #pragma unroll
    for (int off = 32; off > 0; off >>= 1) ss += __shfl_xor(ss, off);
    __shared__ double red[4];
    if ((tid & 63) == 0) red[tid >> 6] = ss;
    __syncthreads();
    double tot = red[0] + red[1] + red[2] + red[3];
    float n32 = (float)fmax(sqrt(tot), 1e-12);
    const float4* g4 = (const float4*)gamma;
    float4 gv = g4[tid];
    float4 o;
    o.x = __fmul_rn(__fmul_rn(__fdiv_rn(v.x, n32), gv.x), 32.0f);
    o.y = __fmul_rn(__fmul_rn(__fdiv_rn(v.y, n32), gv.y), 32.0f);
    o.z = __fmul_rn(__fmul_rn(__fdiv_rn(v.z, n32), gv.z), 32.0f);
    o.w = __fmul_rn(__fmul_rn(__fdiv_rn(v.w, n32), gv.w), 32.0f);
    ((float4*)(xnf + (size_t)t * DIMV))[tid] = o;
}

// ------- K2: q = xn @ wq^T, fp32 sequential-k FMA chain (BLAS mimic) -------
// 128x128 tile, 128 threads, per-thread 16 rows x 8 cols (acc 128 VGPR).
// K-step 16, double-buffered aligned LDS [16][128].
// Thread (tx,ty): rows m0+ty*16+i, cols n0+tx*4+j and n0+64+tx*4+j.
__global__ __launch_bounds__(128) void peer_qgemm(const float* __restrict__ A,
                                                  const float* __restrict__ Bm,
                                                  float* __restrict__ C)
{
    __shared__ float As[2][16][128];
    __shared__ float Bs[2][16][128];
    int tid = threadIdx.x;               // 0..127
    int m0 = blockIdx.y * 128, n0 = blockIdx.x * 128;
    int tx = tid & 15, ty = tid >> 4;    // ty 0..7
    float acc[16][8] = {};
    // loader: thread tid stages row tid of A-tile and B-tile (16 k's each)
    float4 av0 = *(const float4*)(A  + (long)(m0 + tid) * 1024 + 0);
    float4 av1 = *(const float4*)(A  + (long)(m0 + tid) * 1024 + 4);
    float4 av2 = *(const float4*)(A  + (long)(m0 + tid) * 1024 + 8);
    float4 av3 = *(const float4*)(A  + (long)(m0 + tid) * 1024 + 12);
    float4 bv0 = *(const float4*)(Bm + (long)(n0 + tid) * 1024 + 0);
    float4 bv1 = *(const float4*)(Bm + (long)(n0 + tid) * 1024 + 4);
    float4 bv2 = *(const float4*)(Bm + (long)(n0 + tid) * 1024 + 8);
    float4 bv3 = *(const float4*)(Bm + (long)(n0 + tid) * 1024 + 12);
    #pragma unroll
    for (int j = 0; j < 4; j++) {
        As[0][j][tid]      = ((const float*)&av0)[j];
        As[0][4 + j][tid]  = ((const float*)&av1)[j];
        As[0][8 + j][tid]  = ((const float*)&av2)[j];
        As[0][12 + j][tid] = ((const float*)&av3)[j];
        Bs[0][j][tid]      = ((const float*)&bv0)[j];
        Bs[0][4 + j][tid]  = ((const float*)&bv1)[j];
        Bs[0][8 + j][tid]  = ((const float*)&bv2)[j];
        Bs[0][12 + j][tid] = ((const float*)&bv3)[j];
    }
    __syncthreads();
    int cur = 0;
    for (int k0 = 0; k0 < 1024; k0 += 16) {
        bool more = (k0 + 16) < 1024;
        if (more) {                      // next tile in flight under 2048 FMAs
            av0 = *(const float4*)(A  + (long)(m0 + tid) * 1024 + (k0 + 16));
            av1 = *(const float4*)(A  + (long)(m0 + tid) * 1024 + (k0 + 20));
            av2 = *(const float4*)(A  + (long)(m0 + tid) * 1024 + (k0 + 24));
            av3 = *(const float4*)(A  + (long)(m0 + tid) * 1024 + (k0 + 28));
            bv0 = *(const float4*)(Bm + (long)(n0 + tid) * 1024 + (k0 + 16));
            bv1 = *(const float4*)(Bm + (long)(n0 + tid) * 1024 + (k0 + 20));
            bv2 = *(const float4*)(Bm + (long)(n0 + tid) * 1024 + (k0 + 24));
            bv3 = *(const float4*)(Bm + (long)(n0 + tid) * 1024 + (k0 + 28));
        }
        #pragma unroll
        for (int kk = 0; kk < 16; kk++) {
            float4 a0 = *(const float4*)&As[cur][kk][ty * 16];
            float4 a1 = *(const float4*)&As[cur][kk][ty * 16 + 4];
            float4 a2 = *(const float4*)&As[cur][kk][ty * 16 + 8];
            float4 a3 = *(const float4*)&As[cur][kk][ty * 16 + 12];
            float4 b0 = *(const float4*)&Bs[cur][kk][tx * 4];
            float4 b1 = *(const float4*)&Bs[cur][kk][tx * 4 + 64];
            float ra16[16] = {a0.x,a0.y,a0.z,a0.w, a1.x,a1.y,a1.z,a1.w,
                              a2.x,a2.y,a2.z,a2.w, a3.x,a3.y,a3.z,a3.w};
            float rb8[8]   = {b0.x,b0.y,b0.z,b0.w, b1.x,b1.y,b1.z,b1.w};
            #pragma unroll
            for (int i = 0; i < 16; i++)
                #pragma unroll
                for (int j = 0; j < 8; j++)
                    acc[i][j] = __fmaf_rn(ra16[i], rb8[j], acc[i][j]);
        }
        if (more) {
            int nxt = cur ^ 1;
            #pragma unroll
            for (int j = 0; j < 4; j++) {
                As[nxt][j][tid]      = ((const float*)&av0)[j];
                As[nxt][4 + j][tid]  = ((const float*)&av1)[j];
                As[nxt][8 + j][tid]  = ((const float*)&av2)[j];
                As[nxt][12 + j][tid] = ((const float*)&av3)[j];
                Bs[nxt][j][tid]      = ((const float*)&bv0)[j];
                Bs[nxt][4 + j][tid]  = ((const float*)&bv1)[j];
                Bs[nxt][8 + j][tid]  = ((const float*)&bv2)[j];
                Bs[nxt][12 + j][tid] = ((const float*)&bv3)[j];
            }
            __syncthreads();
            cur = nxt;
        }
    }
    #pragma unroll
    for (int i = 0; i < 16; i++) {
        float4 c0 = {acc[i][0], acc[i][1], acc[i][2], acc[i][3]};
        float4 c1 = {acc[i][4], acc[i][5], acc[i][6], acc[i][7]};
        long r = (long)(m0 + ty * 16 + i) * 8192 + n0;
        *(float4*)(C + r + tx * 4)      = c0;
        *(float4*)(C + r + 64 + tx * 4) = c1;
    }
}

// ------- K3: sim via numpy-einsum SSE pattern: 4-lane mul/add partials -----
__global__ __launch_bounds__(256) void peer_sim(const float* __restrict__ qf,
                                                const float* __restrict__ keys,
                                                float* __restrict__ simf)
{
    int tb = blockIdx.x;      // 0..63 (token tile of 16)
    int z  = blockIdx.y;      // 0..15
    int h = z & 7, p = z >> 3;
    int tid = threadIdx.x;
    __shared__ float4 qs[16][128];
    int t0 = tb * 16;
    long qbase = (long)h * 512 + (long)p * 4096;
    int row = tid >> 4, c0 = (tid & 15) * 8;
    const float4* qrow = (const float4*)(qf + (long)(t0 + row) * 8192 + qbase);
    #pragma unroll
    for (int u = 0; u < 8; u++) qs[row][c0 + u] = qrow[c0 + u];
    __syncthreads();
    int k = tid;
    const float4* krow = (const float4*)(keys + (long)h * 262144 + (long)k * 1024 + (long)p * 512);
    float pa[16][4] = {};
    for (int d4 = 0; d4 < 128; d4++) {
        float4 kv = krow[d4];
        #pragma unroll
        for (int tt = 0; tt < 16; tt++) {
            float4 qv = qs[tt][d4];
            pa[tt][0] = __fadd_rn(pa[tt][0], __fmul_rn(qv.x, kv.x));
            pa[tt][1] = __fadd_rn(pa[tt][1], __fmul_rn(qv.y, kv.y));
            pa[tt][2] = __fadd_rn(pa[tt][2], __fmul_rn(qv.z, kv.z));
            pa[tt][3] = __fadd_rn(pa[tt][3], __fmul_rn(qv.w, kv.w));
        }
    }
    #pragma unroll
    for (int tt = 0; tt < 16; tt++) {
        float s = __fadd_rn(__fadd_rn(pa[tt][0], pa[tt][2]),
                            __fadd_rn(pa[tt][1], pa[tt][3]));
        simf[(long)(t0 + tt) * 4096 + (long)p * 2048 + h * 256 + k] = s;
    }
}

// ---------------- K4: two-stage top-16 on fp32 sims (one wave/(t,h)) -------
__device__ inline void peer_select16(float v[4], int lane, float* outv, int* outi)
{
    for (int iter = 0; iter < 16; iter++) {
        float bv = -INFINITY; int bk = 1 << 30;
        #pragma unroll
        for (int i = 0; i < 4; i++) {
            int k = i * 64 + lane;
            if (v[i] > bv || (v[i] == bv && k < bk)) { bv = v[i]; bk = k; }
        }
        #pragma unroll
        for (int off = 32; off > 0; off >>= 1) {
            float ov = __shfl_xor(bv, off);
            int   ok = __shfl_xor(bk, off);
            if (ov > bv || (ov == bv && ok < bk)) { bv = ov; bk = ok; }
        }
        if (lane == 0) { outv[iter] = bv; outi[iter] = bk; }
        __syncthreads();
        if ((bk & 63) == lane) v[bk >> 6] = -INFINITY;
    }
}

__global__ __launch_bounds__(64) void peer_topk(const float* __restrict__ sim,
                                                float* __restrict__ wsel,
                                                int* __restrict__ esel)
{
    int b = blockIdx.x;           // b = t*8 + h
    int t = b >> 3, h = b & 7;
    int lane = threadIdx.x;
    const float* simx = sim + (size_t)t * 4096 + h * 256;   // p=0
    const float* simy = simx + 2048;                        // p=1
    __shared__ float sxv[16]; __shared__ int sxi[16];
    __shared__ float syv[16]; __shared__ int syi[16];
    __shared__ float cv[16];  __shared__ int cf[16];
    float v[4];
    #pragma unroll
    for (int i = 0; i < 4; i++) v[i] = simx[i*64 + lane];
    peer_select16(v, lane, sxv, sxi);
    __syncthreads();
    #pragma unroll
    for (int i = 0; i < 4; i++) v[i] = simy[i*64 + lane];
    peer_select16(v, lane, syv, syi);
    __syncthreads();
    #pragma unroll
    for (int i = 0; i < 4; i++) {
        int f = i*64 + lane;
        v[i] = __fadd_rn(sxv[f >> 4], syv[f & 15]);
    }
    peer_select16(v, lane, cv, cf);
    __syncthreads();
    double m = (double)cv[0];
    double w = (lane < 16) ? exp((double)cv[lane] - m) : 0.0;
    double Z = w;
    #pragma unroll
    for (int off = 32; off > 0; off >>= 1) Z += __shfl_xor(Z, off);
    if (lane < 16) {
        int f = cf[lane];
        esel[b * 16 + lane] = sxi[f >> 4] * 256 + syi[f & 15];
        wsel[b * 16 + lane] = (float)(w / Z);
    }
}

// ------- K5: fused gather: g = gelu(xn.wd)*w, out = sum g * wu -------------
__global__ __launch_bounds__(256) void peer_downup(const float* __restrict__ xn,
                                                   const float* __restrict__ table_down,
                                                   const float* __restrict__ table_up,
                                                   const int* __restrict__ esel,
                                                   const float* __restrict__ wsel,
                                                   float* __restrict__ out)
{
    int t = blockIdx.x;
    int tid = threadIdx.x;
    int wid = tid >> 6, lane = tid & 63;
    __shared__ float4 xs[256];
    __shared__ float  gs[128];
    __shared__ int    es[128];
    if (tid < 128) es[tid] = esel[t * 128 + tid];
    xs[tid] = ((const float4*)(xn + (size_t)t * DIMV))[tid];
    __syncthreads();
    // ---- down phase: 4 experts in flight per wave ----
    #pragma unroll 4
    for (int jj = 0; jj < 32; jj++) {
        int j = wid * 32 + jj;
        const float4* dr = (const float4*)(table_down + (size_t)es[j] * DIMV);
        double acc = 0.0;
        #pragma unroll
        for (int it = 0; it < 4; it++) {
            int d4 = it * 64 + lane;
            float4 a = xs[d4];
            float4 bb = dr[d4];
            acc = fma((double)a.x, (double)bb.x, acc);
            acc = fma((double)a.y, (double)bb.y, acc);
            acc = fma((double)a.z, (double)bb.z, acc);
            acc = fma((double)a.w, (double)bb.w, acc);
        }
        #pragma unroll
        for (int off = 32; off > 0; off >>= 1) acc += __shfl_xor(acc, off);
        if (lane == 0) {
            double hv = acc;
            double ge = 0.5 * hv * (1.0 + erf(hv * 0.70710678118654752));
            gs[j] = (float)(ge * (double)wsel[t * 128 + j]);
        }
    }
    __syncthreads();
    // ---- up phase ----
    int dbase = tid * 4;
    double a0 = 0, a1 = 0, a2 = 0, a3 = 0;
    #pragma unroll 8
    for (int j = 0; j < 128; j++) {
        const float4 u = *(const float4*)(table_up + (size_t)es[j] * DIMV + dbase);
        double gj = (double)gs[j];
        a0 = fma(gj, (double)u.x, a0); a1 = fma(gj, (double)u.y, a1);
        a2 = fma(gj, (double)u.z, a2); a3 = fma(gj, (double)u.w, a3);
    }
    float4 o = {(float)a0, (float)a1, (float)a2, (float)a3};
    *(float4*)(out + (size_t)t * DIMV + dbase) = o;
}

extern "C" void kernel_launch(void* const* d_in, const int* in_sizes, int n_in,
                              void* d_out, int out_size, void* d_ws, size_t ws_size,
                              hipStream_t stream)
{
    const float* x          = (const float*)d_in[0];
    const float* gamma      = (const float*)d_in[1];
    const float* wq         = (const float*)d_in[2];
    const float* keys       = (const float*)d_in[3];
    const float* table_down = (const float*)d_in[4];
    const float* table_up   = (const float*)d_in[5];
    float* out = (float*)d_out;
    char* wsb  = (char*)d_ws;

    // workspace layout (bytes)
    float* xnf  = (float*)(wsb);                        //  4 MB [1024 x 1024]
    float* qf   = (float*)(wsb + (4ull<<20));           // 32 MB [1024 x 8192]
    float* simf = (float*)(wsb + (36ull<<20));          // 16 MB [1024 x 4096]
    float* wsel = (float*)(wsb + (52ull<<20));          // 512 KB
    int*   esel = (int*)  (wsb + (52ull<<20) + (512ull<<10));
    if (ws_size < (54ull << 20)) return;  // need 54 MB scratch

    // 1) rmsnorm (fp64 norm -> fp32 scale, mimics np fp32 elementwise)
    peer_rmsnorm<<<1024, 256, 0, stream>>>(x, gamma, xnf);

    // 2) q[t,r] = sum_D xn[t,D]*wq[r,D], fp32 sequential-FMA (BLAS mimic)
    peer_qgemm<<<dim3(64, 8, 1), 128, 0, stream>>>(xnf, wq, qf);

    // 3) sim[t, p*2048+h*256+k] via einsum-SSE 4-lane fp32 partials
    peer_sim<<<dim3(64, 16, 1), 256, 0, stream>>>(qf, keys, simf);

    // 4) two-stage top-16 + softmax weights + expert ids
    peer_topk<<<8192, 64, 0, stream>>>(simf, wsel, esel);

    // 5) fused: g = gelu(xn . wd[e]) * w ; out = sum_j g_j * wu[e_j]
    peer_downup<<<1024, 256, 0, stream>>>(xnf, table_down, table_up,
                                          esel, wsel, out);
}